// Round 1
// baseline (257.422 us; speedup 1.0000x reference)
//
#include <hip/hip_runtime.h>
#include <math.h>

// Outputs are a pure function of obs's class (NC=1000 distinct values):
// compute per-class tables once (fp64 trunk for argmin robustness), then
// scatter per batch element. Memory floor = the 134 MB of mandatory writes.

__device__ __forceinline__ float sigmoidf_(float x){ return 1.0f/(1.0f + expf(-x)); }

__global__ __launch_bounds__(128) void per_class_kernel(
    const float* __restrict__ embed,
    const float* __restrict__ W1, const float* __restrict__ b1,
    const float* __restrict__ W2, const float* __restrict__ b2,
    const float* __restrict__ W3, const float* __restrict__ b3,
    const float* __restrict__ Wp, const float* __restrict__ bp,
    const float* __restrict__ cb,
    const float* __restrict__ Wa, const float* __restrict__ ba,
    const float* __restrict__ Ws, const float* __restrict__ bs,
    const float* __restrict__ Wc1, const float* __restrict__ bc1,
    const float* __restrict__ Wc2, const float* __restrict__ bc2,
    const float* __restrict__ Wc3, const float* __restrict__ bc3,
    const float* __restrict__ Wc4, const float* __restrict__ bc4,
    float* __restrict__ am_t, float* __restrict__ sd_t,
    float* __restrict__ cr_t, int* __restrict__ idx_t, float* __restrict__ e_t,
    float* __restrict__ loss_slot, int VQN)
{
    const int c = blockIdx.x;
    const int t = threadIdx.x;     // 0..127
    if (c == 0 && t == 0) *loss_slot = 0.0f;   // d_out is poisoned each call

    __shared__ double Abuf[128];
    __shared__ double Bbuf[128];
    __shared__ double zp[64];
    __shared__ float  qv[64];
    __shared__ double rd[128];
    __shared__ int    ri[128];
    __shared__ float  h1[128], h2[128], h3[32];

    // y = embed[c]
    Abuf[t] = (double)embed[(size_t)c * 128 + t];
    __syncthreads();

    // z1 = relu(y @ W1 + b1)
    double acc = (double)b1[t];
    for (int i = 0; i < 128; ++i) acc = fma(Abuf[i], (double)W1[i * 128 + t], acc);
    Bbuf[t] = acc > 0.0 ? acc : 0.0;
    __syncthreads();

    // z2 = relu(z1 @ W2 + b2)
    acc = (double)b2[t];
    for (int i = 0; i < 128; ++i) acc = fma(Bbuf[i], (double)W2[i * 128 + t], acc);
    Abuf[t] = acc > 0.0 ? acc : 0.0;
    __syncthreads();

    // z3 = relu(z2 @ W3 + b3)
    acc = (double)b3[t];
    for (int i = 0; i < 128; ++i) acc = fma(Abuf[i], (double)W3[i * 128 + t], acc);
    Bbuf[t] = acc > 0.0 ? acc : 0.0;
    __syncthreads();

    // zp = z3 @ Wp + bp   (64 outputs)
    if (t < 64) {
        acc = (double)bp[t];
        for (int i = 0; i < 128; ++i) acc = fma(Bbuf[i], (double)Wp[i * 64 + t], acc);
        zp[t] = acc;
    }
    __syncthreads();

    // VQ argmin over VQN codes; thread t owns codes t, t+128, ...
    double best = 1e300; int bidx = 0;
    for (int k = t; k < VQN; k += 128) {
        const float* crow = cb + (size_t)k * 64;
        double s = 0.0;
        for (int j = 0; j < 64; ++j) { double df = zp[j] - (double)crow[j]; s = fma(df, df, s); }
        if (s < best) { best = s; bidx = k; }
    }
    rd[t] = best; ri[t] = bidx;
    __syncthreads();
    for (int sft = 64; sft > 0; sft >>= 1) {
        if (t < sft) {
            if (rd[t + sft] < rd[t] || (rd[t + sft] == rd[t] && ri[t + sft] < ri[t])) {
                rd[t] = rd[t + sft]; ri[t] = ri[t + sft];
            }
        }
        __syncthreads();
    }
    const int widx = ri[0];
    if (t < 64) qv[t] = cb[(size_t)widx * 64 + t];
    __syncthreads();

    // heads (fp32; q = exact codebook row, tolerance is ~2% of max)
    float la = ba[t], ls = bs[t], l1 = bc1[t];
    for (int j = 0; j < 64; ++j) {
        float qj = qv[j];
        la = fmaf(qj, Wa[j * 128 + t], la);
        ls = fmaf(qj, Ws[j * 128 + t], ls);
        l1 = fmaf(qj, Wc1[j * 128 + t], l1);
    }
    am_t[(size_t)c * 128 + t] = sigmoidf_(la);
    sd_t[(size_t)c * 128 + t] = sigmoidf_(ls) * 1.0f + 1e-8f;   // SQUISH=1.0
    h1[t] = sigmoidf_(l1);
    __syncthreads();

    float l2 = bc2[t];
    for (int i = 0; i < 128; ++i) l2 = fmaf(h1[i], Wc2[i * 128 + t], l2);
    h2[t] = sigmoidf_(l2);
    __syncthreads();

    if (t < 32) {
        float l3 = bc3[t];
        for (int i = 0; i < 128; ++i) l3 = fmaf(h2[i], Wc3[i * 32 + t], l3);
        h3[t] = sigmoidf_(l3);
    }
    __syncthreads();

    if (t == 0) {
        float l4 = bc4[0];
        for (int i = 0; i < 32; ++i) l4 = fmaf(h3[i], Wc4[i], l4);
        cr_t[c] = l4;              // no sigmoid on final critic layer
        idx_t[c] = widx;
        double e = 0.0;
        for (int j = 0; j < 64; ++j) { double df = (double)qv[j] - zp[j]; e = fma(df, df, e); }
        e_t[c] = (float)e;         // sum over 64 dims of (quant-z)^2
    }
}

// actor_mean + scale_diag scatter: one float4 per thread, fully coalesced writes.
__global__ __launch_bounds__(256) void scatter_vec_kernel(
    const int* __restrict__ obs,
    const float4* __restrict__ am_t, const float4* __restrict__ sd_t,
    float4* __restrict__ out, int B)
{
    int gid = blockIdx.x * 256 + threadIdx.x;
    int half = B * 32;                       // B*128/4
    if (gid < half) {
        int b = gid >> 5;                    // 32 float4 per row
        int j = gid & 31;
        out[gid] = am_t[(size_t)obs[b] * 32 + j];
    } else {
        int g = gid - half;
        int b = g >> 5;
        int j = g & 31;
        out[gid] = sd_t[(size_t)obs[b] * 32 + j];
    }
}

// critic + idx scatter and vq_loss reduction (one atomic per block)
__global__ __launch_bounds__(256) void scatter_scalar_kernel(
    const int* __restrict__ obs, const float* __restrict__ cr_t,
    const int* __restrict__ idx_t, const float* __restrict__ e_t,
    float* __restrict__ out_critic, float* __restrict__ out_idx,
    float* __restrict__ out_loss, int B, float scale)
{
    int b = blockIdx.x * 256 + threadIdx.x;
    float e = 0.0f;
    if (b < B) {
        int o = obs[b];
        out_critic[b] = cr_t[o];
        out_idx[b]    = (float)idx_t[o];
        e = e_t[o];
    }
    __shared__ float red[256];
    red[threadIdx.x] = e;
    __syncthreads();
    for (int s = 128; s > 0; s >>= 1) {
        if (threadIdx.x < s) red[threadIdx.x] += red[threadIdx.x + s];
        __syncthreads();
    }
    if (threadIdx.x == 0) atomicAdd(out_loss, red[0] * scale);
}

extern "C" void kernel_launch(void* const* d_in, const int* in_sizes, int n_in,
                              void* d_out, int out_size, void* d_ws, size_t ws_size,
                              hipStream_t stream)
{
    const int*   obs   = (const int*)  d_in[0];
    const float* embed = (const float*)d_in[1];
    const float* W1    = (const float*)d_in[2];
    const float* b1    = (const float*)d_in[3];
    const float* W2    = (const float*)d_in[4];
    const float* b2    = (const float*)d_in[5];
    const float* W3    = (const float*)d_in[6];
    const float* b3    = (const float*)d_in[7];
    const float* Wp    = (const float*)d_in[8];
    const float* bp    = (const float*)d_in[9];
    const float* cb    = (const float*)d_in[10];
    const float* Wa    = (const float*)d_in[11];
    const float* ba    = (const float*)d_in[12];
    const float* Ws    = (const float*)d_in[13];
    const float* bs    = (const float*)d_in[14];
    const float* Wc1   = (const float*)d_in[15];
    const float* bc1   = (const float*)d_in[16];
    const float* Wc2   = (const float*)d_in[17];
    const float* bc2   = (const float*)d_in[18];
    const float* Wc3   = (const float*)d_in[19];
    const float* bc3   = (const float*)d_in[20];
    const float* Wc4   = (const float*)d_in[21];
    const float* bc4   = (const float*)d_in[22];

    const int B   = in_sizes[0];
    const int NC  = in_sizes[1] / 128;
    const int VQN = in_sizes[10] / 64;

    // workspace tables (~1.04 MB for NC=1000)
    float* am_t = (float*)d_ws;
    float* sd_t = am_t + (size_t)NC * 128;
    float* cr_t = sd_t + (size_t)NC * 128;
    float* e_t  = cr_t + NC;
    int*   idx_t = (int*)(e_t + NC);

    float* out = (float*)d_out;
    const size_t cr_off   = (size_t)B * 256;     // after am (B*128) + sd (B*128)
    const size_t loss_off = cr_off + (size_t)B;
    const size_t idx_off  = loss_off + 1;

    per_class_kernel<<<NC, 128, 0, stream>>>(
        embed, W1, b1, W2, b2, W3, b3, Wp, bp, cb,
        Wa, ba, Ws, bs, Wc1, bc1, Wc2, bc2, Wc3, bc3, Wc4, bc4,
        am_t, sd_t, cr_t, idx_t, e_t, out + loss_off, VQN);

    int vec_threads = 2 * B * 32;                // 2 * B * 128 / 4 float4s
    scatter_vec_kernel<<<vec_threads / 256, 256, 0, stream>>>(
        obs, (const float4*)am_t, (const float4*)sd_t, (float4*)out, B);

    scatter_scalar_kernel<<<(B + 255) / 256, 256, 0, stream>>>(
        obs, cr_t, idx_t, e_t, out + cr_off, out + idx_off, out + loss_off,
        B, 1.25f / ((float)B * 64.0f));
}

// Round 3
// 255.364 us; speedup vs baseline: 1.0081x; 1.0081x over previous
//
#include <hip/hip_runtime.h>
#include <math.h>

// Outputs are a pure function of obs's class (NC=1000 distinct values):
// compute per-class tables once (fp64 trunk for argmin robustness), then
// scatter per batch element. Memory floor = the 134 MB of mandatory writes.
//
// R3: native ext_vector_type(4) for nontemporal float4 stores (HIP float4
// is a class type the builtin rejects); 4-way ILP fp64 chains from R2.

typedef float f4 __attribute__((ext_vector_type(4)));

__device__ __forceinline__ float sigmoidf_(float x){ return 1.0f/(1.0f + expf(-x)); }

__global__ __launch_bounds__(128) void per_class_kernel(
    const float* __restrict__ embed,
    const float* __restrict__ W1, const float* __restrict__ b1,
    const float* __restrict__ W2, const float* __restrict__ b2,
    const float* __restrict__ W3, const float* __restrict__ b3,
    const float* __restrict__ Wp, const float* __restrict__ bp,
    const float* __restrict__ cb,
    const float* __restrict__ Wa, const float* __restrict__ ba,
    const float* __restrict__ Ws, const float* __restrict__ bs,
    const float* __restrict__ Wc1, const float* __restrict__ bc1,
    const float* __restrict__ Wc2, const float* __restrict__ bc2,
    const float* __restrict__ Wc3, const float* __restrict__ bc3,
    const float* __restrict__ Wc4, const float* __restrict__ bc4,
    float* __restrict__ am_t, float* __restrict__ sd_t,
    float* __restrict__ cr_t, int* __restrict__ idx_t, float* __restrict__ e_t,
    float* __restrict__ loss_slot, int VQN)
{
    const int c = blockIdx.x;
    const int t = threadIdx.x;     // 0..127
    if (c == 0 && t == 0) *loss_slot = 0.0f;   // d_out is poisoned each call

    __shared__ double Abuf[128];
    __shared__ double Bbuf[128];
    __shared__ double zp[64];
    __shared__ float  qv[64];
    __shared__ double rd[128];
    __shared__ int    ri[128];
    __shared__ float  h1[128], h2[128], h3[32];

    // y = embed[c]
    Abuf[t] = (double)embed[(size_t)c * 128 + t];
    __syncthreads();

    // z1 = relu(y @ W1 + b1) — 4 independent accumulators (chain len 32)
    {
        double a0 = (double)b1[t], a1 = 0.0, a2 = 0.0, a3 = 0.0;
        for (int i = 0; i < 128; i += 4) {
            a0 = fma(Abuf[i+0], (double)W1[(i+0) * 128 + t], a0);
            a1 = fma(Abuf[i+1], (double)W1[(i+1) * 128 + t], a1);
            a2 = fma(Abuf[i+2], (double)W1[(i+2) * 128 + t], a2);
            a3 = fma(Abuf[i+3], (double)W1[(i+3) * 128 + t], a3);
        }
        double acc = (a0 + a1) + (a2 + a3);
        Bbuf[t] = acc > 0.0 ? acc : 0.0;
    }
    __syncthreads();

    // z2 = relu(z1 @ W2 + b2)
    {
        double a0 = (double)b2[t], a1 = 0.0, a2 = 0.0, a3 = 0.0;
        for (int i = 0; i < 128; i += 4) {
            a0 = fma(Bbuf[i+0], (double)W2[(i+0) * 128 + t], a0);
            a1 = fma(Bbuf[i+1], (double)W2[(i+1) * 128 + t], a1);
            a2 = fma(Bbuf[i+2], (double)W2[(i+2) * 128 + t], a2);
            a3 = fma(Bbuf[i+3], (double)W2[(i+3) * 128 + t], a3);
        }
        double acc = (a0 + a1) + (a2 + a3);
        Abuf[t] = acc > 0.0 ? acc : 0.0;
    }
    __syncthreads();

    // z3 = relu(z2 @ W3 + b3)
    {
        double a0 = (double)b3[t], a1 = 0.0, a2 = 0.0, a3 = 0.0;
        for (int i = 0; i < 128; i += 4) {
            a0 = fma(Abuf[i+0], (double)W3[(i+0) * 128 + t], a0);
            a1 = fma(Abuf[i+1], (double)W3[(i+1) * 128 + t], a1);
            a2 = fma(Abuf[i+2], (double)W3[(i+2) * 128 + t], a2);
            a3 = fma(Abuf[i+3], (double)W3[(i+3) * 128 + t], a3);
        }
        double acc = (a0 + a1) + (a2 + a3);
        Bbuf[t] = acc > 0.0 ? acc : 0.0;
    }
    __syncthreads();

    // zp = z3 @ Wp + bp   (64 outputs)
    if (t < 64) {
        double a0 = (double)bp[t], a1 = 0.0, a2 = 0.0, a3 = 0.0;
        for (int i = 0; i < 128; i += 4) {
            a0 = fma(Bbuf[i+0], (double)Wp[(i+0) * 64 + t], a0);
            a1 = fma(Bbuf[i+1], (double)Wp[(i+1) * 64 + t], a1);
            a2 = fma(Bbuf[i+2], (double)Wp[(i+2) * 64 + t], a2);
            a3 = fma(Bbuf[i+3], (double)Wp[(i+3) * 64 + t], a3);
        }
        zp[t] = (a0 + a1) + (a2 + a3);
    }
    __syncthreads();

    // VQ argmin over VQN codes; thread t owns codes t, t+128, ...
    double best = 1e300; int bidx = 0;
    for (int k = t; k < VQN; k += 128) {
        const float* crow = cb + (size_t)k * 64;
        double s0 = 0.0, s1 = 0.0;
        for (int j = 0; j < 64; j += 2) {
            double d0 = zp[j+0] - (double)crow[j+0];
            double d1 = zp[j+1] - (double)crow[j+1];
            s0 = fma(d0, d0, s0);
            s1 = fma(d1, d1, s1);
        }
        double s = s0 + s1;
        if (s < best) { best = s; bidx = k; }
    }
    rd[t] = best; ri[t] = bidx;
    __syncthreads();
    for (int sft = 64; sft > 0; sft >>= 1) {
        if (t < sft) {
            if (rd[t + sft] < rd[t] || (rd[t + sft] == rd[t] && ri[t + sft] < ri[t])) {
                rd[t] = rd[t + sft]; ri[t] = ri[t + sft];
            }
        }
        __syncthreads();
    }
    const int widx = ri[0];
    if (t < 64) qv[t] = cb[(size_t)widx * 64 + t];
    __syncthreads();

    // heads (fp32; q = exact codebook row, tolerance is ~2% of max)
    {
        float la0 = ba[t],  la1 = 0.0f;
        float ls0 = bs[t],  ls1 = 0.0f;
        float l10 = bc1[t], l11 = 0.0f;
        for (int j = 0; j < 64; j += 2) {
            float q0 = qv[j], q1 = qv[j+1];
            la0 = fmaf(q0, Wa[j * 128 + t], la0);
            la1 = fmaf(q1, Wa[(j+1) * 128 + t], la1);
            ls0 = fmaf(q0, Ws[j * 128 + t], ls0);
            ls1 = fmaf(q1, Ws[(j+1) * 128 + t], ls1);
            l10 = fmaf(q0, Wc1[j * 128 + t], l10);
            l11 = fmaf(q1, Wc1[(j+1) * 128 + t], l11);
        }
        am_t[(size_t)c * 128 + t] = sigmoidf_(la0 + la1);
        sd_t[(size_t)c * 128 + t] = sigmoidf_(ls0 + ls1) * 1.0f + 1e-8f;   // SQUISH=1.0
        h1[t] = sigmoidf_(l10 + l11);
    }
    __syncthreads();

    {
        float l20 = bc2[t], l21 = 0.0f;
        for (int i = 0; i < 128; i += 2) {
            l20 = fmaf(h1[i],   Wc2[i * 128 + t],     l20);
            l21 = fmaf(h1[i+1], Wc2[(i+1) * 128 + t], l21);
        }
        h2[t] = sigmoidf_(l20 + l21);
    }
    __syncthreads();

    if (t < 32) {
        float l30 = bc3[t], l31 = 0.0f;
        for (int i = 0; i < 128; i += 2) {
            l30 = fmaf(h2[i],   Wc3[i * 32 + t],     l30);
            l31 = fmaf(h2[i+1], Wc3[(i+1) * 32 + t], l31);
        }
        h3[t] = sigmoidf_(l30 + l31);
    }
    __syncthreads();

    if (t == 0) {
        float l4 = bc4[0];
        for (int i = 0; i < 32; ++i) l4 = fmaf(h3[i], Wc4[i], l4);
        cr_t[c] = l4;              // no sigmoid on final critic layer
        idx_t[c] = widx;
        double e0 = 0.0, e1 = 0.0;
        for (int j = 0; j < 64; j += 2) {
            double d0 = (double)qv[j]   - zp[j];
            double d1 = (double)qv[j+1] - zp[j+1];
            e0 = fma(d0, d0, e0); e1 = fma(d1, d1, e1);
        }
        e_t[c] = (float)(e0 + e1); // sum over 64 dims of (quant-z)^2
    }
}

// actor_mean + scale_diag scatter: one float4 per thread, fully coalesced
// nontemporal writes (output is never re-read; keep class tables in L2).
__global__ __launch_bounds__(256) void scatter_vec_kernel(
    const int* __restrict__ obs,
    const f4* __restrict__ am_t, const f4* __restrict__ sd_t,
    f4* __restrict__ out, int B)
{
    int gid = blockIdx.x * 256 + threadIdx.x;
    int half = B * 32;                       // B*128/4
    if (gid < half) {
        int b = gid >> 5;                    // 32 float4 per row
        int j = gid & 31;
        __builtin_nontemporal_store(am_t[(size_t)obs[b] * 32 + j], &out[gid]);
    } else {
        int g = gid - half;
        int b = g >> 5;
        int j = g & 31;
        __builtin_nontemporal_store(sd_t[(size_t)obs[b] * 32 + j], &out[gid]);
    }
}

// critic + idx scatter and vq_loss reduction (one atomic per block)
__global__ __launch_bounds__(256) void scatter_scalar_kernel(
    const int* __restrict__ obs, const float* __restrict__ cr_t,
    const int* __restrict__ idx_t, const float* __restrict__ e_t,
    float* __restrict__ out_critic, float* __restrict__ out_idx,
    float* __restrict__ out_loss, int B, float scale)
{
    int b = blockIdx.x * 256 + threadIdx.x;
    float e = 0.0f;
    if (b < B) {
        int o = obs[b];
        __builtin_nontemporal_store(cr_t[o], &out_critic[b]);
        __builtin_nontemporal_store((float)idx_t[o], &out_idx[b]);
        e = e_t[o];
    }
    __shared__ float red[256];
    red[threadIdx.x] = e;
    __syncthreads();
    for (int s = 128; s > 0; s >>= 1) {
        if (threadIdx.x < s) red[threadIdx.x] += red[threadIdx.x + s];
        __syncthreads();
    }
    if (threadIdx.x == 0) atomicAdd(out_loss, red[0] * scale);
}

extern "C" void kernel_launch(void* const* d_in, const int* in_sizes, int n_in,
                              void* d_out, int out_size, void* d_ws, size_t ws_size,
                              hipStream_t stream)
{
    const int*   obs   = (const int*)  d_in[0];
    const float* embed = (const float*)d_in[1];
    const float* W1    = (const float*)d_in[2];
    const float* b1    = (const float*)d_in[3];
    const float* W2    = (const float*)d_in[4];
    const float* b2    = (const float*)d_in[5];
    const float* W3    = (const float*)d_in[6];
    const float* b3    = (const float*)d_in[7];
    const float* Wp    = (const float*)d_in[8];
    const float* bp    = (const float*)d_in[9];
    const float* cb    = (const float*)d_in[10];
    const float* Wa    = (const float*)d_in[11];
    const float* ba    = (const float*)d_in[12];
    const float* Ws    = (const float*)d_in[13];
    const float* bs    = (const float*)d_in[14];
    const float* Wc1   = (const float*)d_in[15];
    const float* bc1   = (const float*)d_in[16];
    const float* Wc2   = (const float*)d_in[17];
    const float* bc2   = (const float*)d_in[18];
    const float* Wc3   = (const float*)d_in[19];
    const float* bc3   = (const float*)d_in[20];
    const float* Wc4   = (const float*)d_in[21];
    const float* bc4   = (const float*)d_in[22];

    const int B   = in_sizes[0];
    const int NC  = in_sizes[1] / 128;
    const int VQN = in_sizes[10] / 64;

    // workspace tables (~1.04 MB for NC=1000)
    float* am_t = (float*)d_ws;
    float* sd_t = am_t + (size_t)NC * 128;
    float* cr_t = sd_t + (size_t)NC * 128;
    float* e_t  = cr_t + NC;
    int*   idx_t = (int*)(e_t + NC);

    float* out = (float*)d_out;
    const size_t cr_off   = (size_t)B * 256;     // after am (B*128) + sd (B*128)
    const size_t loss_off = cr_off + (size_t)B;
    const size_t idx_off  = loss_off + 1;

    per_class_kernel<<<NC, 128, 0, stream>>>(
        embed, W1, b1, W2, b2, W3, b3, Wp, bp, cb,
        Wa, ba, Ws, bs, Wc1, bc1, Wc2, bc2, Wc3, bc3, Wc4, bc4,
        am_t, sd_t, cr_t, idx_t, e_t, out + loss_off, VQN);

    int vec_threads = 2 * B * 32;                // 2 * B * 128 / 4 float4s
    scatter_vec_kernel<<<vec_threads / 256, 256, 0, stream>>>(
        obs, (const f4*)am_t, (const f4*)sd_t, (f4*)out, B);

    scatter_scalar_kernel<<<(B + 255) / 256, 256, 0, stream>>>(
        obs, cr_t, idx_t, e_t, out + cr_off, out + idx_off, out + loss_off,
        B, 1.25f / ((float)B * 64.0f));
}